// Round 3
// baseline (802.194 us; speedup 1.0000x reference)
//
#include <hip/hip_runtime.h>
#include <stdint.h>

#define NN 50000
#define NE 800000
#define HID 128
#define NG 64
#define BN_EPS 1e-5f

typedef __bf16 bf16x8 __attribute__((ext_vector_type(8)));
typedef float floatx4 __attribute__((ext_vector_type(4)));

__device__ __forceinline__ float b2f(unsigned short u) {
    union { unsigned int i; float f; } x; x.i = ((unsigned int)u) << 16; return x.f;
}
__device__ __forceinline__ unsigned short f2b(float f) {
    union { float f; unsigned int i; } x; x.f = f; unsigned int i = x.i;
    if ((i & 0x7f800000u) == 0x7f800000u) return (unsigned short)(i >> 16); // inf/nan
    return (unsigned short)((i + 0x7fffu + ((i >> 16) & 1u)) >> 16);        // RNE
}

// ---------------- setup kernels ----------------
__global__ void k_init(int* deg, int* gstart, int* gend, float* bnstats,
                       float* pool_sum, int* pool_max) {
    int i = blockIdx.x * 256 + threadIdx.x;
    if (i < NN) deg[i] = 0;
    if (i < NG) { gstart[i] = NN; gend[i] = -1; }
    if (i < 3 * 256) bnstats[i] = 0.f;
    if (i < NG * HID) { pool_sum[i] = 0.f; pool_max[i] = 0; }
}

// x fp32 -> bf16 packed
__global__ void k_cvt(const float* __restrict__ x, unsigned short* xb) {
    int i = blockIdx.x * 256 + threadIdx.x;  // over NN*64 dwords (2 feats each)
    if (i >= NN * 64) return;
    float2 v = ((const float2*)x)[i];
    ((unsigned int*)xb)[i] = (((unsigned int)f2b(v.y)) << 16) | f2b(v.x);
}

__global__ void k_hist(const int* __restrict__ dst, int* deg) {
    int e = blockIdx.x * 256 + threadIdx.x;
    if (e < NE) atomicAdd(&deg[dst[e]], 1);
}

__global__ void k_bounds(const int* __restrict__ batch, int* gstart, int* gend) {
    int i = blockIdx.x * 256 + threadIdx.x;
    if (i >= NN) return;
    int g = batch[i];
    if (i == 0 || batch[i - 1] != g) atomicMin(&gstart[g], i);
    if (i == NN - 1 || batch[i + 1] != g) atomicMax(&gend[g], i);
}

#define SCAN_CHUNK ((NN + 1023) / 1024)
__global__ void __launch_bounds__(1024) k_scan(const int* __restrict__ deg,
                                               int* row_start, int* cursor) {
    __shared__ int lds[1024];
    int t = threadIdx.x;
    int start = t * SCAN_CHUNK;
    int s = 0;
    for (int i = 0; i < SCAN_CHUNK; ++i) {
        int idx = start + i;
        if (idx < NN) s += deg[idx];
    }
    lds[t] = s;
    __syncthreads();
    for (int off = 1; off < 1024; off <<= 1) {
        int v = (t >= off) ? lds[t - off] : 0;
        __syncthreads();
        lds[t] += v;
        __syncthreads();
    }
    int run = lds[t] - s;  // exclusive prefix
    for (int i = 0; i < SCAN_CHUNK; ++i) {
        int idx = start + i;
        if (idx < NN) { row_start[idx] = run; cursor[idx] = run; run += deg[idx]; }
    }
    if (t == 1023) row_start[NN] = run;
}

__global__ void k_scatter(const int* __restrict__ src, const int* __restrict__ dst,
                          int* cursor, int* col) {
    int e = blockIdx.x * 256 + threadIdx.x;
    if (e < NE) {
        int p = atomicAdd(&cursor[dst[e]], 1);
        col[p] = src[e];
    }
}

// Pre-transpose fp32 [Wl;Wr] (256x128) into bf16 MFMA B-fragment order:
// Bp[layer][nt][kk][lane][j] = Wcat[kk*32+(lane>>4)*8+j][nt*16+(lane&15)]
__global__ void k_prep(const float* __restrict__ Wl0, const float* __restrict__ Wr0,
                       const float* __restrict__ Wl1, const float* __restrict__ Wr1,
                       const float* __restrict__ Wl2, const float* __restrict__ Wr2,
                       unsigned short* Bp) {
    int idx = blockIdx.x * 256 + threadIdx.x;
    if (idx >= 3 * 32768) return;
    int layer = idx >> 15;
    int r = idx & 32767;
    int nt = r >> 12, kk = (r >> 9) & 7, l = (r >> 3) & 63, j = r & 7;
    int k = kk * 32 + (l >> 4) * 8 + j;
    int n = nt * 16 + (l & 15);
    const float* Wl = layer == 0 ? Wl0 : (layer == 1 ? Wl1 : Wl2);
    const float* Wr = layer == 0 ? Wr0 : (layer == 1 ? Wr1 : Wr2);
    Bp[idx] = f2b((k < 128) ? Wl[k * 128 + n] : Wr[(k - 128) * 128 + n]);
}

// ---------------- per-layer kernels ----------------
// mean aggregation: one wave per node, lane handles 2 features (one dword)
__global__ void k_agg(const unsigned short* __restrict__ h, const int* __restrict__ row_start,
                      const int* __restrict__ col, unsigned short* agg) {
    int wid = threadIdx.x >> 6, lane = threadIdx.x & 63;
    int node = blockIdx.x * 4 + wid;
    if (node >= NN) return;
    int s = row_start[node], e = row_start[node + 1];
    const unsigned int* h32 = (const unsigned int*)h;
    float a0 = 0.f, a1 = 0.f;
    for (int j = s; j < e; ++j) {
        int u = col[j];
        unsigned int v = h32[u * 64 + lane];
        a0 += __uint_as_float(v << 16);
        a1 += __uint_as_float(v & 0xffff0000u);
    }
    float inv = (e > s) ? 1.f / (float)(e - s) : 0.f;
    ((unsigned int*)agg)[node * 64 + lane] =
        (((unsigned int)f2b(a1 * inv)) << 16) | f2b(a0 * inv);
}

// buf[M,128] <- [buf|h][M,256] @ Wcat[256,128], bf16 in-place (wave owns its 16 rows;
// all A loads are consumed by MFMAs before epilogue stores; no __restrict__ on alias).
__global__ void __launch_bounds__(256) k_gemm(unsigned short* buf,
                                              const unsigned short* h,
                                              const unsigned short* Bp) {
    int wid = threadIdx.x >> 6, lane = threadIdx.x & 63;
    int m_base = (blockIdx.x * 4 + wid) * 16;
    if (m_base >= NN) return;
    int m = lane & 15, q = lane >> 4;
    int row = m_base + m;  // always < NN (NN multiple-of-16 tiles fit exactly at tail)
    const bf16x8* A0 = (const bf16x8*)buf + (size_t)row * 16;
    const bf16x8* A1 = (const bf16x8*)h + (size_t)row * 16;
    const bf16x8* B = (const bf16x8*)Bp;
    floatx4 acc[8];
#pragma unroll
    for (int nt = 0; nt < 8; ++nt) acc[nt] = (floatx4){0.f, 0.f, 0.f, 0.f};
#pragma unroll
    for (int kk = 0; kk < 8; ++kk) {
        bf16x8 a = (kk < 4) ? A0[kk * 4 + q] : A1[(kk - 4) * 4 + q];
#pragma unroll
        for (int nt = 0; nt < 8; ++nt) {
            bf16x8 b = B[(nt * 8 + kk) * 64 + lane];
            acc[nt] = __builtin_amdgcn_mfma_f32_16x16x32_bf16(a, b, acc[nt], 0, 0, 0);
        }
    }
#pragma unroll
    for (int nt = 0; nt < 8; ++nt) {
        int c = nt * 16 + m;  // C/D: col = lane&15
#pragma unroll
        for (int reg = 0; reg < 4; ++reg) {
            int r = m_base + q * 4 + reg;  // C/D: row = quad*4+reg
            if (r < NN) buf[(size_t)r * 128 + c] = f2b(acc[nt][reg]);
        }
    }
}

__global__ void k_stat(const unsigned short* __restrict__ pre, float* bnstat) {
    int t = threadIdx.x;
    int c = t & 127, half = t >> 7;
    float s = 0.f, ss = 0.f;
    for (int r = blockIdx.x * 2 + half; r < NN; r += gridDim.x * 2) {
        float v = b2f(pre[(size_t)r * 128 + c]);
        s += v; ss += v * v;
    }
    atomicAdd(&bnstat[c], s);
    atomicAdd(&bnstat[128 + c], ss);
}

// BN+ReLU in place (bf16 buffer), gamma/beta fp32
__global__ void k_norm(unsigned short* buf, const float* __restrict__ bnstat,
                       const float* __restrict__ gamma, const float* __restrict__ beta) {
    __shared__ float s_sc[128], s_sh[128];
    int t = threadIdx.x;
    if (t < 128) {
        float mu = bnstat[t] * (1.f / NN);
        float var = bnstat[128 + t] * (1.f / NN) - mu * mu;
        float sc = gamma[t] * rsqrtf(var + BN_EPS);
        s_sc[t] = sc;
        s_sh[t] = beta[t] - mu * sc;
    }
    __syncthreads();
    unsigned int* p2 = (unsigned int*)buf;
    int total = NN * 64;
    for (int idx = blockIdx.x * blockDim.x + t; idx < total; idx += gridDim.x * blockDim.x) {
        int c2 = (idx & 63) * 2;
        unsigned int v = p2[idx];
        float r0 = fmaxf(b2f((unsigned short)(v & 0xffffu)) * s_sc[c2] + s_sh[c2], 0.f);
        float r1 = fmaxf(b2f((unsigned short)(v >> 16)) * s_sc[c2 + 1] + s_sh[c2 + 1], 0.f);
        p2[idx] = (((unsigned int)f2b(r1)) << 16) | f2b(r0);
    }
}

// ---------------- pooling + head ----------------
__global__ void k_pool(const unsigned short* __restrict__ h, const int* __restrict__ gstart,
                       const int* __restrict__ gend, float* pool_sum, int* pool_max) {
    int g = blockIdx.x >> 3, chunk = blockIdx.x & 7;
    int s = gstart[g], e = gend[g];
    if (s > e) return;
    int cnt = e - s + 1;
    int per = (cnt + 7) >> 3;
    int r0 = s + chunk * per;
    int r1 = min(r0 + per, e + 1);
    int c = threadIdx.x & 127, half = threadIdx.x >> 7;
    float sm = 0.f, mx = 0.f;  // post-relu values are >= 0
    for (int r = r0 + half; r < r1; r += 2) {
        float v = b2f(h[(size_t)r * 128 + c]);
        sm += v;
        mx = fmaxf(mx, v);
    }
    atomicAdd(&pool_sum[g * 128 + c], sm);
    atomicMax(&pool_max[g * 128 + c], __float_as_int(mx));  // valid for >=0 floats
}

__global__ void __launch_bounds__(128) k_head(
    const float* __restrict__ pool_sum, const int* __restrict__ pool_max,
    const int* __restrict__ gstart, const int* __restrict__ gend,
    const float* __restrict__ gfeats,
    const float* __restrict__ W1, const float* __restrict__ bs1,
    const float* __restrict__ W2, const float* __restrict__ bs2,
    const float* __restrict__ W3, const float* __restrict__ bs3,
    float* out) {
    __shared__ float m[288];
    __shared__ float o1[128];
    __shared__ float o2[64];
    int g = blockIdx.x, t = threadIdx.x;
    int s = gstart[g], e = gend[g];
    int cint = e - s + 1;
    float cnt = (float)(cint < 1 ? 1 : cint);
    if (t < 128) {
        m[t] = pool_sum[g * 128 + t] / cnt;
        m[128 + t] = __int_as_float(pool_max[g * 128 + t]);
    }
    if (t < 32) m[256 + t] = gfeats[g * 32 + t];
    __syncthreads();
    float acc = bs1[t];
    for (int k = 0; k < 288; ++k) acc += m[k] * W1[k * 128 + t];
    o1[t] = fmaxf(acc, 0.f);
    __syncthreads();
    if (t < 64) {
        float a2 = bs2[t];
        for (int k = 0; k < 128; ++k) a2 += o1[k] * W2[k * 64 + t];
        o2[t] = fmaxf(a2, 0.f);
    }
    __syncthreads();
    if (t < 64) {
        float p = o2[t] * W3[t];
#pragma unroll
        for (int off = 32; off; off >>= 1) p += __shfl_down(p, off, 64);
        if (t == 0) out[g] = p + bs3[0];
    }
}

// ---------------- launch ----------------
extern "C" void kernel_launch(void* const* d_in, const int* in_sizes, int n_in,
                              void* d_out, int out_size, void* d_ws, size_t ws_size,
                              hipStream_t stream) {
    const float* x = (const float*)d_in[0];
    const int* ei = (const int*)d_in[1];
    const int* batch = (const int*)d_in[2];
    const float* gfeats = (const float*)d_in[3];
    const float *Wl[3], *Wr[3], *gma[3], *bta[3];
    for (int i = 0; i < 3; ++i) {
        Wl[i] = (const float*)d_in[4 + 5 * i];
        // d_in[5+5i] = bl (cancelled by BatchNorm; unused)
        Wr[i] = (const float*)d_in[6 + 5 * i];
        gma[i] = (const float*)d_in[7 + 5 * i];
        bta[i] = (const float*)d_in[8 + 5 * i];
    }
    const float* W1 = (const float*)d_in[19];
    const float* bs1 = (const float*)d_in[20];
    const float* W2 = (const float*)d_in[21];
    const float* bs2 = (const float*)d_in[22];
    const float* W3 = (const float*)d_in[23];
    const float* bs3 = (const float*)d_in[24];

    char* p = (char*)d_ws;
    auto alloc = [&](size_t bytes) -> char* {
        char* r = p;
        p += (bytes + 255) & ~(size_t)255;
        return r;
    };
    // total ~42.5 MB
    int* deg = (int*)alloc(NN * 4);
    int* row_start = (int*)alloc((NN + 1) * 4);
    int* cursor = (int*)alloc(NN * 4);
    int* col = (int*)alloc(NE * 4);
    int* gstart = (int*)alloc(NG * 4);
    int* gend = (int*)alloc(NG * 4);
    float* bnstats = (float*)alloc(3 * 256 * 4);
    float* pool_sum = (float*)alloc(NG * HID * 4);
    int* pool_max = (int*)alloc(NG * HID * 4);
    unsigned short* Bp = (unsigned short*)alloc(3 * 32768 * 2);
    unsigned short* xb = (unsigned short*)alloc((size_t)NN * 128 * 2);
    unsigned short* b0 = (unsigned short*)alloc((size_t)NN * 128 * 2);
    unsigned short* b1 = (unsigned short*)alloc((size_t)NN * 128 * 2);

    const int* srcv = ei;
    const int* dstv = ei + NE;

    k_init<<<(NN + 255) / 256, 256, 0, stream>>>(deg, gstart, gend, bnstats, pool_sum, pool_max);
    k_cvt<<<(NN * 64 + 255) / 256, 256, 0, stream>>>(x, xb);
    k_hist<<<(NE + 255) / 256, 256, 0, stream>>>(dstv, deg);
    k_bounds<<<(NN + 255) / 256, 256, 0, stream>>>(batch, gstart, gend);
    k_scan<<<1, 1024, 0, stream>>>(deg, row_start, cursor);
    k_scatter<<<(NE + 255) / 256, 256, 0, stream>>>(srcv, dstv, cursor, col);
    k_prep<<<(3 * 32768 + 255) / 256, 256, 0, stream>>>(Wl[0], Wr[0], Wl[1], Wr[1], Wl[2], Wr[2], Bp);

    // layer rotation: hin -> work buffer (agg+gemm+norm all in work buffer)
    const unsigned short* hin = xb;
    unsigned short* work[3] = {b0, b1, b0};
    for (int l = 0; l < 3; ++l) {
        unsigned short* w = work[l];
        k_agg<<<(NN + 3) / 4, 256, 0, stream>>>(hin, row_start, col, w);
        k_gemm<<<(NN + 63) / 64, 256, 0, stream>>>(w, (const unsigned short*)hin, Bp + l * 32768);
        k_stat<<<256, 256, 0, stream>>>(w, bnstats + l * 256);
        k_norm<<<1024, 256, 0, stream>>>(w, bnstats + l * 256, gma[l], bta[l]);
        hin = w;
    }
    k_pool<<<NG * 8, 256, 0, stream>>>(hin, gstart, gend, pool_sum, pool_max);
    k_head<<<NG, 128, 0, stream>>>(pool_sum, pool_max, gstart, gend, gfeats,
                                   W1, bs1, W2, bs2, W3, bs3, (float*)d_out);
}

// Round 4
// 532.392 us; speedup vs baseline: 1.5068x; 1.5068x over previous
//
#include <hip/hip_runtime.h>
#include <stdint.h>

#define NN 50000
#define NE 800000
#define HID 128
#define NG 64
#define BN_EPS 1e-5f
#define SCAN_BLOCKS 196  // 196*256 = 50176 >= NN

typedef __bf16 bf16x8 __attribute__((ext_vector_type(8)));
typedef float floatx4 __attribute__((ext_vector_type(4)));

__device__ __forceinline__ float b2f(unsigned short u) {
    union { unsigned int i; float f; } x; x.i = ((unsigned int)u) << 16; return x.f;
}
__device__ __forceinline__ unsigned short f2b(float f) {
    union { float f; unsigned int i; } x; x.f = f; unsigned int i = x.i;
    if ((i & 0x7f800000u) == 0x7f800000u) return (unsigned short)(i >> 16); // inf/nan
    return (unsigned short)((i + 0x7fffu + ((i >> 16) & 1u)) >> 16);        // RNE
}

// ---------------- setup ----------------
// fused: zero-init everything + fp32->bf16 convert of x
__global__ void k_setup(const float* __restrict__ x, unsigned short* xb, int* deg,
                        int* gstart, int* gend, float* bnstats,
                        float* pool_sum, int* pool_max) {
    int i = blockIdx.x * 256 + threadIdx.x;
    if (i < NN * 64) {
        float2 v = ((const float2*)x)[i];
        ((unsigned int*)xb)[i] = (((unsigned int)f2b(v.y)) << 16) | f2b(v.x);
    }
    if (i < NN) deg[i] = 0;
    if (i < NG) { gstart[i] = NN; gend[i] = -1; }
    if (i < 3 * 256) bnstats[i] = 0.f;
    if (i < NG * HID) { pool_sum[i] = 0.f; pool_max[i] = 0; }
}

// fused: degree histogram (over NE) + per-graph row bounds (over NN)
__global__ void k_histb(const int* __restrict__ dst, int* deg,
                        const int* __restrict__ batch, int* gstart, int* gend) {
    int e = blockIdx.x * 256 + threadIdx.x;
    if (e < NE) atomicAdd(&deg[dst[e]], 1);
    if (e < NN) {
        int g = batch[e];
        if (e == 0 || batch[e - 1] != g) atomicMin(&gstart[g], e);
        if (e == NN - 1 || batch[e + 1] != g) atomicMax(&gend[g], e);
    }
}

// ---------------- hierarchical exclusive scan of deg ----------------
__global__ void k_scan1(const int* __restrict__ deg, int* blocksum) {
    __shared__ int lds[256];
    int t = threadIdx.x, i = blockIdx.x * 256 + t;
    lds[t] = (i < NN) ? deg[i] : 0;
    __syncthreads();
    for (int off = 128; off > 0; off >>= 1) {
        if (t < off) lds[t] += lds[t + off];
        __syncthreads();
    }
    if (t == 0) blocksum[blockIdx.x] = lds[0];
}

__global__ void k_scan2(const int* __restrict__ blocksum, int* blockoff, int* row_start) {
    __shared__ int lds[256];
    int t = threadIdx.x;
    int v = (t < SCAN_BLOCKS) ? blocksum[t] : 0;
    lds[t] = v;
    __syncthreads();
    for (int off = 1; off < 256; off <<= 1) {
        int u = (t >= off) ? lds[t - off] : 0;
        __syncthreads();
        lds[t] += u;
        __syncthreads();
    }
    if (t < SCAN_BLOCKS) blockoff[t] = lds[t] - v;  // exclusive
    if (t == 255) row_start[NN] = lds[255];         // total == NE
}

__global__ void k_scan3(const int* __restrict__ deg, const int* __restrict__ blockoff,
                        int* row_start, int* cursor) {
    __shared__ int lds[256];
    int t = threadIdx.x, i = blockIdx.x * 256 + t;
    int v = (i < NN) ? deg[i] : 0;
    lds[t] = v;
    __syncthreads();
    for (int off = 1; off < 256; off <<= 1) {
        int u = (t >= off) ? lds[t - off] : 0;
        __syncthreads();
        lds[t] += u;
        __syncthreads();
    }
    if (i < NN) {
        int ex = blockoff[blockIdx.x] + lds[t] - v;
        row_start[i] = ex;
        cursor[i] = ex;
    }
}

__global__ void k_scatter(const int* __restrict__ src, const int* __restrict__ dst,
                          int* cursor, int* col) {
    int e = blockIdx.x * 256 + threadIdx.x;
    if (e < NE) {
        int p = atomicAdd(&cursor[dst[e]], 1);
        col[p] = src[e];
    }
}

// Pre-transpose fp32 [Wl;Wr] (256x128) into bf16 MFMA B-fragment order:
// Bp[layer][nt][kk][lane][j] = Wcat[kk*32+(lane>>4)*8+j][nt*16+(lane&15)]
__global__ void k_prep(const float* __restrict__ Wl0, const float* __restrict__ Wr0,
                       const float* __restrict__ Wl1, const float* __restrict__ Wr1,
                       const float* __restrict__ Wl2, const float* __restrict__ Wr2,
                       unsigned short* Bp) {
    int idx = blockIdx.x * 256 + threadIdx.x;
    if (idx >= 3 * 32768) return;
    int layer = idx >> 15;
    int r = idx & 32767;
    int nt = r >> 12, kk = (r >> 9) & 7, l = (r >> 3) & 63, j = r & 7;
    int k = kk * 32 + (l >> 4) * 8 + j;
    int n = nt * 16 + (l & 15);
    const float* Wl = layer == 0 ? Wl0 : (layer == 1 ? Wl1 : Wl2);
    const float* Wr = layer == 0 ? Wr0 : (layer == 1 ? Wr1 : Wr2);
    Bp[idx] = f2b((k < 128) ? Wl[k * 128 + n] : Wr[(k - 128) * 128 + n]);
}

// ---------------- per-layer kernels ----------------
// mean aggregation: one wave per node. Indices preloaded (1 coalesced load per 64
// neighbors), broadcast via shfl; gather unrolled x4 for independent loads in flight.
__global__ void k_agg(const unsigned short* __restrict__ h, const int* __restrict__ row_start,
                      const int* __restrict__ col, unsigned short* agg) {
    int wid = threadIdx.x >> 6, lane = threadIdx.x & 63;
    int node = blockIdx.x * 4 + wid;
    if (node >= NN) return;
    int s = row_start[node], e = row_start[node + 1];
    const unsigned int* h32 = (const unsigned int*)h;
    float a0 = 0.f, a1 = 0.f;
    for (int base = s; base < e; base += 64) {
        int n = min(64, e - base);
        int idx = (base + lane < e) ? col[base + lane] : 0;
        int j = 0;
        for (; j + 4 <= n; j += 4) {
            int u0 = __shfl(idx, j, 64);
            int u1 = __shfl(idx, j + 1, 64);
            int u2 = __shfl(idx, j + 2, 64);
            int u3 = __shfl(idx, j + 3, 64);
            unsigned int v0 = h32[u0 * 64 + lane];
            unsigned int v1 = h32[u1 * 64 + lane];
            unsigned int v2 = h32[u2 * 64 + lane];
            unsigned int v3 = h32[u3 * 64 + lane];
            a0 += (__uint_as_float(v0 << 16) + __uint_as_float(v1 << 16)) +
                  (__uint_as_float(v2 << 16) + __uint_as_float(v3 << 16));
            a1 += (__uint_as_float(v0 & 0xffff0000u) + __uint_as_float(v1 & 0xffff0000u)) +
                  (__uint_as_float(v2 & 0xffff0000u) + __uint_as_float(v3 & 0xffff0000u));
        }
        for (; j < n; ++j) {
            int u = __shfl(idx, j, 64);
            unsigned int v = h32[u * 64 + lane];
            a0 += __uint_as_float(v << 16);
            a1 += __uint_as_float(v & 0xffff0000u);
        }
    }
    float inv = (e > s) ? 1.f / (float)(e - s) : 0.f;
    ((unsigned int*)agg)[node * 64 + lane] =
        (((unsigned int)f2b(a1 * inv)) << 16) | f2b(a0 * inv);
}

// buf[M,128] <- [buf|h][M,256] @ Wcat[256,128], bf16 in-place (wave owns its 16 rows;
// all A loads consumed by MFMAs before epilogue stores; no __restrict__ on alias).
__global__ void __launch_bounds__(256) k_gemm(unsigned short* buf,
                                              const unsigned short* h,
                                              const unsigned short* Bp) {
    int wid = threadIdx.x >> 6, lane = threadIdx.x & 63;
    int m_base = (blockIdx.x * 4 + wid) * 16;
    if (m_base >= NN) return;
    int m = lane & 15, q = lane >> 4;
    int row = m_base + m;
    const bf16x8* A0 = (const bf16x8*)buf + (size_t)row * 16;
    const bf16x8* A1 = (const bf16x8*)h + (size_t)row * 16;
    const bf16x8* B = (const bf16x8*)Bp;
    floatx4 acc[8];
#pragma unroll
    for (int nt = 0; nt < 8; ++nt) acc[nt] = (floatx4){0.f, 0.f, 0.f, 0.f};
#pragma unroll
    for (int kk = 0; kk < 8; ++kk) {
        bf16x8 a = (kk < 4) ? A0[kk * 4 + q] : A1[(kk - 4) * 4 + q];
#pragma unroll
        for (int nt = 0; nt < 8; ++nt) {
            bf16x8 b = B[(nt * 8 + kk) * 64 + lane];
            acc[nt] = __builtin_amdgcn_mfma_f32_16x16x32_bf16(a, b, acc[nt], 0, 0, 0);
        }
    }
#pragma unroll
    for (int nt = 0; nt < 8; ++nt) {
        int c = nt * 16 + m;  // C/D: col = lane&15
#pragma unroll
        for (int reg = 0; reg < 4; ++reg) {
            int r = m_base + q * 4 + reg;  // C/D: row = quad*4+reg
            if (r < NN) buf[(size_t)r * 128 + c] = f2b(acc[nt][reg]);
        }
    }
}

__global__ void k_stat(const unsigned short* __restrict__ pre, float* bnstat) {
    int t = threadIdx.x;
    int c = t & 127, half = t >> 7;
    float s = 0.f, ss = 0.f;
    for (int r = blockIdx.x * 2 + half; r < NN; r += gridDim.x * 2) {
        float v = b2f(pre[(size_t)r * 128 + c]);
        s += v; ss += v * v;
    }
    atomicAdd(&bnstat[c], s);
    atomicAdd(&bnstat[128 + c], ss);
}

// BN+ReLU in place (bf16 buffer), gamma/beta fp32
__global__ void k_norm(unsigned short* buf, const float* __restrict__ bnstat,
                       const float* __restrict__ gamma, const float* __restrict__ beta) {
    __shared__ float s_sc[128], s_sh[128];
    int t = threadIdx.x;
    if (t < 128) {
        float mu = bnstat[t] * (1.f / NN);
        float var = bnstat[128 + t] * (1.f / NN) - mu * mu;
        float sc = gamma[t] * rsqrtf(var + BN_EPS);
        s_sc[t] = sc;
        s_sh[t] = beta[t] - mu * sc;
    }
    __syncthreads();
    unsigned int* p2 = (unsigned int*)buf;
    int total = NN * 64;
    for (int idx = blockIdx.x * blockDim.x + t; idx < total; idx += gridDim.x * blockDim.x) {
        int c2 = (idx & 63) * 2;
        unsigned int v = p2[idx];
        float r0 = fmaxf(b2f((unsigned short)(v & 0xffffu)) * s_sc[c2] + s_sh[c2], 0.f);
        float r1 = fmaxf(b2f((unsigned short)(v >> 16)) * s_sc[c2 + 1] + s_sh[c2 + 1], 0.f);
        p2[idx] = (((unsigned int)f2b(r1)) << 16) | f2b(r0);
    }
}

// ---------------- pooling + head ----------------
__global__ void k_pool(const unsigned short* __restrict__ h, const int* __restrict__ gstart,
                       const int* __restrict__ gend, float* pool_sum, int* pool_max) {
    int g = blockIdx.x >> 3, chunk = blockIdx.x & 7;
    int s = gstart[g], e = gend[g];
    if (s > e) return;
    int cnt = e - s + 1;
    int per = (cnt + 7) >> 3;
    int r0 = s + chunk * per;
    int r1 = min(r0 + per, e + 1);
    int c = threadIdx.x & 127, half = threadIdx.x >> 7;
    float sm = 0.f, mx = 0.f;  // post-relu values are >= 0
    for (int r = r0 + half; r < r1; r += 2) {
        float v = b2f(h[(size_t)r * 128 + c]);
        sm += v;
        mx = fmaxf(mx, v);
    }
    atomicAdd(&pool_sum[g * 128 + c], sm);
    atomicMax(&pool_max[g * 128 + c], __float_as_int(mx));  // valid for >=0 floats
}

__global__ void __launch_bounds__(128) k_head(
    const float* __restrict__ pool_sum, const int* __restrict__ pool_max,
    const int* __restrict__ gstart, const int* __restrict__ gend,
    const float* __restrict__ gfeats,
    const float* __restrict__ W1, const float* __restrict__ bs1,
    const float* __restrict__ W2, const float* __restrict__ bs2,
    const float* __restrict__ W3, const float* __restrict__ bs3,
    float* out) {
    __shared__ float m[288];
    __shared__ float o1[128];
    __shared__ float o2[64];
    int g = blockIdx.x, t = threadIdx.x;
    int s = gstart[g], e = gend[g];
    int cint = e - s + 1;
    float cnt = (float)(cint < 1 ? 1 : cint);
    if (t < 128) {
        m[t] = pool_sum[g * 128 + t] / cnt;
        m[128 + t] = __int_as_float(pool_max[g * 128 + t]);
    }
    if (t < 32) m[256 + t] = gfeats[g * 32 + t];
    __syncthreads();
    float acc = bs1[t];
    for (int k = 0; k < 288; ++k) acc += m[k] * W1[k * 128 + t];
    o1[t] = fmaxf(acc, 0.f);
    __syncthreads();
    if (t < 64) {
        float a2 = bs2[t];
        for (int k = 0; k < 128; ++k) a2 += o1[k] * W2[k * 64 + t];
        o2[t] = fmaxf(a2, 0.f);
    }
    __syncthreads();
    if (t < 64) {
        float p = o2[t] * W3[t];
#pragma unroll
        for (int off = 32; off; off >>= 1) p += __shfl_down(p, off, 64);
        if (t == 0) out[g] = p + bs3[0];
    }
}

// ---------------- launch ----------------
extern "C" void kernel_launch(void* const* d_in, const int* in_sizes, int n_in,
                              void* d_out, int out_size, void* d_ws, size_t ws_size,
                              hipStream_t stream) {
    const float* x = (const float*)d_in[0];
    const int* ei = (const int*)d_in[1];
    const int* batch = (const int*)d_in[2];
    const float* gfeats = (const float*)d_in[3];
    const float *Wl[3], *Wr[3], *gma[3], *bta[3];
    for (int i = 0; i < 3; ++i) {
        Wl[i] = (const float*)d_in[4 + 5 * i];
        // d_in[5+5i] = bl (cancelled by BatchNorm; unused)
        Wr[i] = (const float*)d_in[6 + 5 * i];
        gma[i] = (const float*)d_in[7 + 5 * i];
        bta[i] = (const float*)d_in[8 + 5 * i];
    }
    const float* W1 = (const float*)d_in[19];
    const float* bs1 = (const float*)d_in[20];
    const float* W2 = (const float*)d_in[21];
    const float* bs2 = (const float*)d_in[22];
    const float* W3 = (const float*)d_in[23];
    const float* bs3 = (const float*)d_in[24];

    char* p = (char*)d_ws;
    auto alloc = [&](size_t bytes) -> char* {
        char* r = p;
        p += (bytes + 255) & ~(size_t)255;
        return r;
    };
    // total ~42.5 MB
    int* deg = (int*)alloc(NN * 4);
    int* row_start = (int*)alloc((NN + 1) * 4);
    int* cursor = (int*)alloc(NN * 4);
    int* col = (int*)alloc(NE * 4);
    int* gstart = (int*)alloc(NG * 4);
    int* gend = (int*)alloc(NG * 4);
    float* bnstats = (float*)alloc(3 * 256 * 4);
    float* pool_sum = (float*)alloc(NG * HID * 4);
    int* pool_max = (int*)alloc(NG * HID * 4);
    int* blocksum = (int*)alloc(SCAN_BLOCKS * 4);
    int* blockoff = (int*)alloc(SCAN_BLOCKS * 4);
    unsigned short* Bp = (unsigned short*)alloc(3 * 32768 * 2);
    unsigned short* xb = (unsigned short*)alloc((size_t)NN * 128 * 2);
    unsigned short* b0 = (unsigned short*)alloc((size_t)NN * 128 * 2);
    unsigned short* b1 = (unsigned short*)alloc((size_t)NN * 128 * 2);

    const int* srcv = ei;
    const int* dstv = ei + NE;

    k_setup<<<(NN * 64 + 255) / 256, 256, 0, stream>>>(x, xb, deg, gstart, gend,
                                                       bnstats, pool_sum, pool_max);
    k_histb<<<(NE + 255) / 256, 256, 0, stream>>>(dstv, deg, batch, gstart, gend);
    k_scan1<<<SCAN_BLOCKS, 256, 0, stream>>>(deg, blocksum);
    k_scan2<<<1, 256, 0, stream>>>(blocksum, blockoff, row_start);
    k_scan3<<<SCAN_BLOCKS, 256, 0, stream>>>(deg, blockoff, row_start, cursor);
    k_scatter<<<(NE + 255) / 256, 256, 0, stream>>>(srcv, dstv, cursor, col);
    k_prep<<<(3 * 32768 + 255) / 256, 256, 0, stream>>>(Wl[0], Wr[0], Wl[1], Wr[1], Wl[2], Wr[2], Bp);

    const unsigned short* hin = xb;
    unsigned short* work[3] = {b0, b1, b0};
    for (int l = 0; l < 3; ++l) {
        unsigned short* w = work[l];
        k_agg<<<(NN + 3) / 4, 256, 0, stream>>>(hin, row_start, col, w);
        k_gemm<<<(NN + 63) / 64, 256, 0, stream>>>(w, (const unsigned short*)hin, Bp + l * 32768);
        k_stat<<<512, 256, 0, stream>>>(w, bnstats + l * 256);
        k_norm<<<1024, 256, 0, stream>>>(w, bnstats + l * 256, gma[l], bta[l]);
        hin = w;
    }
    k_pool<<<NG * 8, 256, 0, stream>>>(hin, gstart, gend, pool_sum, pool_max);
    k_head<<<NG, 128, 0, stream>>>(pool_sum, pool_max, gstart, gend, gfeats,
                                   W1, bs1, W2, bs2, W3, bs3, (float*)d_out);
}

// Round 5
// 505.390 us; speedup vs baseline: 1.5873x; 1.0534x over previous
//
#include <hip/hip_runtime.h>
#include <stdint.h>

#define NN 50000
#define NE 800000
#define HID 128
#define NG 64
#define BN_EPS 1e-5f
#define SCAN_BLOCKS 196  // 196*256 = 50176 >= NN
#define GEMM_BLOCKS ((NN + 127) / 128)

typedef __bf16 bf16x8 __attribute__((ext_vector_type(8)));
typedef float floatx4 __attribute__((ext_vector_type(4)));

__device__ __forceinline__ float b2f(unsigned short u) {
    union { unsigned int i; float f; } x; x.i = ((unsigned int)u) << 16; return x.f;
}
__device__ __forceinline__ float blo(unsigned int d) { return __uint_as_float(d << 16); }
__device__ __forceinline__ float bhi(unsigned int d) { return __uint_as_float(d & 0xffff0000u); }
__device__ __forceinline__ unsigned short f2b(float f) {
    union { float f; unsigned int i; } x; x.f = f; unsigned int i = x.i;
    if ((i & 0x7f800000u) == 0x7f800000u) return (unsigned short)(i >> 16); // inf/nan
    return (unsigned short)((i + 0x7fffu + ((i >> 16) & 1u)) >> 16);        // RNE
}
__device__ __forceinline__ unsigned int pack2(float f0, float f1) {
    return (((unsigned int)f2b(f1)) << 16) | f2b(f0);
}

// ---------------- setup ----------------
__global__ void k_setup(const float* __restrict__ x, unsigned short* xb, int* deg,
                        int* gstart, int* gend, float* bnstats,
                        float* pool_sum, int* pool_max) {
    int i = blockIdx.x * 256 + threadIdx.x;
    if (i < NN * 64) {
        float2 v = ((const float2*)x)[i];
        ((unsigned int*)xb)[i] = pack2(v.x, v.y);
    }
    if (i < NN) deg[i] = 0;
    if (i < NG) { gstart[i] = NN; gend[i] = -1; }
    if (i < 3 * 256) bnstats[i] = 0.f;
    if (i < NG * HID) { pool_sum[i] = 0.f; pool_max[i] = 0; }
}

// fused: degree histogram (over NE) + per-graph row bounds (over NN)
__global__ void k_histb(const int* __restrict__ dst, int* deg,
                        const int* __restrict__ batch, int* gstart, int* gend) {
    int e = blockIdx.x * 256 + threadIdx.x;
    if (e < NE) atomicAdd(&deg[dst[e]], 1);
    if (e < NN) {
        int g = batch[e];
        if (e == 0 || batch[e - 1] != g) atomicMin(&gstart[g], e);
        if (e == NN - 1 || batch[e + 1] != g) atomicMax(&gend[g], e);
    }
}

// ---------------- hierarchical exclusive scan of deg ----------------
__global__ void k_scan1(const int* __restrict__ deg, int* blocksum) {
    __shared__ int lds[256];
    int t = threadIdx.x, i = blockIdx.x * 256 + t;
    lds[t] = (i < NN) ? deg[i] : 0;
    __syncthreads();
    for (int off = 128; off > 0; off >>= 1) {
        if (t < off) lds[t] += lds[t + off];
        __syncthreads();
    }
    if (t == 0) blocksum[blockIdx.x] = lds[0];
}

__global__ void k_scan2(const int* __restrict__ blocksum, int* blockoff, int* row_start) {
    __shared__ int lds[256];
    int t = threadIdx.x;
    int v = (t < SCAN_BLOCKS) ? blocksum[t] : 0;
    lds[t] = v;
    __syncthreads();
    for (int off = 1; off < 256; off <<= 1) {
        int u = (t >= off) ? lds[t - off] : 0;
        __syncthreads();
        lds[t] += u;
        __syncthreads();
    }
    if (t < SCAN_BLOCKS) blockoff[t] = lds[t] - v;  // exclusive
    if (t == 255) row_start[NN] = lds[255];         // total == NE
}

__global__ void k_scan3(const int* __restrict__ deg, const int* __restrict__ blockoff,
                        int* row_start, int* cursor) {
    __shared__ int lds[256];
    int t = threadIdx.x, i = blockIdx.x * 256 + t;
    int v = (i < NN) ? deg[i] : 0;
    lds[t] = v;
    __syncthreads();
    for (int off = 1; off < 256; off <<= 1) {
        int u = (t >= off) ? lds[t - off] : 0;
        __syncthreads();
        lds[t] += u;
        __syncthreads();
    }
    if (i < NN) {
        int ex = blockoff[blockIdx.x] + lds[t] - v;
        row_start[i] = ex;
        cursor[i] = ex;
    }
}

__global__ void k_scatter(const int* __restrict__ src, const int* __restrict__ dst,
                          int* cursor, int* col) {
    int e = blockIdx.x * 256 + threadIdx.x;
    if (e < NE) {
        int d = __builtin_nontemporal_load(&dst[e]);
        int s = __builtin_nontemporal_load(&src[e]);
        int p = atomicAdd(&cursor[d], 1);
        __builtin_nontemporal_store(s, &col[p]);
    }
}

// Pre-transpose fp32 [Wl;Wr] (256x128) into bf16 MFMA B-fragment order:
// Bp[layer][nt][kk][lane][j] = Wcat[kk*32+(lane>>4)*8+j][nt*16+(lane&15)]
__global__ void k_prep(const float* __restrict__ Wl0, const float* __restrict__ Wr0,
                       const float* __restrict__ Wl1, const float* __restrict__ Wr1,
                       const float* __restrict__ Wl2, const float* __restrict__ Wr2,
                       unsigned short* Bp) {
    int idx = blockIdx.x * 256 + threadIdx.x;
    if (idx >= 3 * 32768) return;
    int layer = idx >> 15;
    int r = idx & 32767;
    int nt = r >> 12, kk = (r >> 9) & 7, l = (r >> 3) & 63, j = r & 7;
    int k = kk * 32 + (l >> 4) * 8 + j;
    int n = nt * 16 + (l & 15);
    const float* Wl = layer == 0 ? Wl0 : (layer == 1 ? Wl1 : Wl2);
    const float* Wr = layer == 0 ? Wr0 : (layer == 1 ? Wr1 : Wr2);
    Bp[idx] = f2b((k < 128) ? Wl[k * 128 + n] : Wr[(k - 128) * 128 + n]);
}

// ---------------- per-layer kernels ----------------
// mean aggregation: one wave per node; 4 edges in flight per iteration
// (slot = lane>>4 picks the edge, sub = lane&15 picks the 16B chunk of the row).
__global__ void k_agg(const unsigned short* __restrict__ h, const int* __restrict__ row_start,
                      const int* __restrict__ col, unsigned short* __restrict__ agg) {
    int wid = threadIdx.x >> 6, lane = threadIdx.x & 63;
    int node = blockIdx.x * 4 + wid;
    if (node >= NN) return;
    int s = row_start[node], e = row_start[node + 1];
    int slot = lane >> 4, sub = lane & 15;
    const uint4* h4 = (const uint4*)h;  // one row = 16 uint4 (256B)
    float a0 = 0.f, a1 = 0.f, a2 = 0.f, a3 = 0.f, a4 = 0.f, a5 = 0.f, a6 = 0.f, a7 = 0.f;
    const uint4 z = {0u, 0u, 0u, 0u};
    for (int base = s; base < e; base += 64) {
        int n = min(64, e - base);
        int idx = (base + lane < e) ? col[base + lane] : 0;
        for (int j = 0; j < n; j += 8) {
            int my0 = j + slot, my1 = j + 4 + slot;
            int u0 = __shfl(idx, my0 & 63, 64);
            int u1 = __shfl(idx, my1 & 63, 64);
            uint4 v0 = (my0 < n) ? h4[(size_t)u0 * 16 + sub] : z;
            uint4 v1 = (my1 < n) ? h4[(size_t)u1 * 16 + sub] : z;
            a0 += blo(v0.x) + blo(v1.x);  a1 += bhi(v0.x) + bhi(v1.x);
            a2 += blo(v0.y) + blo(v1.y);  a3 += bhi(v0.y) + bhi(v1.y);
            a4 += blo(v0.z) + blo(v1.z);  a5 += bhi(v0.z) + bhi(v1.z);
            a6 += blo(v0.w) + blo(v1.w);  a7 += bhi(v0.w) + bhi(v1.w);
        }
    }
#define RED(v) v += __shfl_xor(v, 16, 64); v += __shfl_xor(v, 32, 64)
    RED(a0); RED(a1); RED(a2); RED(a3); RED(a4); RED(a5); RED(a6); RED(a7);
#undef RED
    if (slot == 0) {
        float inv = (e > s) ? 1.f / (float)(e - s) : 0.f;
        uint4 o;
        o.x = pack2(a0 * inv, a1 * inv);
        o.y = pack2(a2 * inv, a3 * inv);
        o.z = pack2(a4 * inv, a5 * inv);
        o.w = pack2(a6 * inv, a7 * inv);
        ((uint4*)agg)[(size_t)node * 16 + sub] = o;
    }
}

// buf[M,128] <- [buf|h][M,256] @ Wcat[256,128], bf16 in-place; BN stats fused.
// Block = 4 waves, each wave 32 rows (2 M-tiles); B staged in LDS (64KB).
__global__ void __launch_bounds__(256) k_gemm(unsigned short* buf,
                                              const unsigned short* __restrict__ h,
                                              const unsigned short* __restrict__ Bp,
                                              float* bnstat) {
    __shared__ unsigned short Bs[32768];  // 64KB: B fragments; reused as float[256] stats
    int t = threadIdx.x;
    {
        const uint4* s4 = (const uint4*)Bp;
        uint4* d4 = (uint4*)Bs;
        for (int i = t; i < 4096; i += 256) d4[i] = s4[i];
    }
    __syncthreads();
    int wid = t >> 6, lane = t & 63;
    int m = lane & 15, q = lane >> 4;
    int mbase = blockIdx.x * 128 + wid * 32;
    bool active = mbase < NN;
    float s[8] = {0, 0, 0, 0, 0, 0, 0, 0};
    float ss[8] = {0, 0, 0, 0, 0, 0, 0, 0};
    if (active) {
        int row0 = mbase + m;                       // always < NN when active
        int row1 = min(mbase + 16 + m, NN - 1);     // clamp tail (garbage rows masked later)
        const bf16x8* Abuf = (const bf16x8*)buf;
        const bf16x8* Ah = (const bf16x8*)h;
        const bf16x8* B = (const bf16x8*)Bs;
        size_t b0 = (size_t)row0 * 16, b1 = (size_t)row1 * 16;
        floatx4 acc[2][8];
#pragma unroll
        for (int mt = 0; mt < 2; ++mt)
#pragma unroll
            for (int nt = 0; nt < 8; ++nt) acc[mt][nt] = (floatx4){0.f, 0.f, 0.f, 0.f};
#pragma unroll
        for (int kk = 0; kk < 8; ++kk) {
            bf16x8 a0 = (kk < 4) ? Abuf[b0 + kk * 4 + q] : Ah[b0 + (kk - 4) * 4 + q];
            bf16x8 a1 = (kk < 4) ? Abuf[b1 + kk * 4 + q] : Ah[b1 + (kk - 4) * 4 + q];
#pragma unroll
            for (int nt = 0; nt < 8; ++nt) {
                bf16x8 b = B[(nt * 8 + kk) * 64 + lane];
                acc[0][nt] = __builtin_amdgcn_mfma_f32_16x16x32_bf16(a0, b, acc[0][nt], 0, 0, 0);
                acc[1][nt] = __builtin_amdgcn_mfma_f32_16x16x32_bf16(a1, b, acc[1][nt], 0, 0, 0);
            }
        }
        // epilogue: store bf16 + accumulate per-column stats
#pragma unroll
        for (int mt = 0; mt < 2; ++mt)
#pragma unroll
            for (int nt = 0; nt < 8; ++nt) {
                int c = nt * 16 + m;  // C/D: col = lane&15
#pragma unroll
                for (int reg = 0; reg < 4; ++reg) {
                    int r = mbase + mt * 16 + q * 4 + reg;  // C/D: row = quad*4+reg
                    if (r < NN) {
                        float v = acc[mt][nt][reg];
                        buf[(size_t)r * 128 + c] = f2b(v);
                        s[nt] += v;
                        ss[nt] += v * v;
                    }
                }
            }
#pragma unroll
        for (int nt = 0; nt < 8; ++nt) {
            s[nt] += __shfl_xor(s[nt], 16, 64);  s[nt] += __shfl_xor(s[nt], 32, 64);
            ss[nt] += __shfl_xor(ss[nt], 16, 64); ss[nt] += __shfl_xor(ss[nt], 32, 64);
        }
    }
    __syncthreads();  // all waves done reading Bs
    float* stf = (float*)Bs;
    if (t < 256) stf[t] = 0.f;
    __syncthreads();
    if (active && lane < 16) {
#pragma unroll
        for (int nt = 0; nt < 8; ++nt) {
            int c = nt * 16 + m;
            atomicAdd(&stf[c], s[nt]);
            atomicAdd(&stf[128 + c], ss[nt]);
        }
    }
    __syncthreads();
    if (t < 256) atomicAdd(&bnstat[t], stf[t]);
}

// BN+ReLU in place (bf16 buffer), gamma/beta fp32
__global__ void k_norm(unsigned short* buf, const float* __restrict__ bnstat,
                       const float* __restrict__ gamma, const float* __restrict__ beta) {
    __shared__ float s_sc[128], s_sh[128];
    int t = threadIdx.x;
    if (t < 128) {
        float mu = bnstat[t] * (1.f / NN);
        float var = bnstat[128 + t] * (1.f / NN) - mu * mu;
        float sc = gamma[t] * rsqrtf(var + BN_EPS);
        s_sc[t] = sc;
        s_sh[t] = beta[t] - mu * sc;
    }
    __syncthreads();
    unsigned int* p2 = (unsigned int*)buf;
    int total = NN * 64;
    for (int idx = blockIdx.x * blockDim.x + t; idx < total; idx += gridDim.x * blockDim.x) {
        int c2 = (idx & 63) * 2;
        unsigned int v = p2[idx];
        float r0 = fmaxf(b2f((unsigned short)(v & 0xffffu)) * s_sc[c2] + s_sh[c2], 0.f);
        float r1 = fmaxf(b2f((unsigned short)(v >> 16)) * s_sc[c2 + 1] + s_sh[c2 + 1], 0.f);
        p2[idx] = pack2(r0, r1);
    }
}

// ---------------- pooling + head ----------------
__global__ void k_pool(const unsigned short* __restrict__ h, const int* __restrict__ gstart,
                       const int* __restrict__ gend, float* pool_sum, int* pool_max) {
    int g = blockIdx.x >> 3, chunk = blockIdx.x & 7;
    int s = gstart[g], e = gend[g];
    if (s > e) return;
    int cnt = e - s + 1;
    int per = (cnt + 7) >> 3;
    int r0 = s + chunk * per;
    int r1 = min(r0 + per, e + 1);
    int c = threadIdx.x & 127, half = threadIdx.x >> 7;
    float sm = 0.f, mx = 0.f;  // post-relu values are >= 0
    for (int r = r0 + half; r < r1; r += 2) {
        float v = b2f(h[(size_t)r * 128 + c]);
        sm += v;
        mx = fmaxf(mx, v);
    }
    atomicAdd(&pool_sum[g * 128 + c], sm);
    atomicMax(&pool_max[g * 128 + c], __float_as_int(mx));  // valid for >=0 floats
}

__global__ void __launch_bounds__(128) k_head(
    const float* __restrict__ pool_sum, const int* __restrict__ pool_max,
    const int* __restrict__ gstart, const int* __restrict__ gend,
    const float* __restrict__ gfeats,
    const float* __restrict__ W1, const float* __restrict__ bs1,
    const float* __restrict__ W2, const float* __restrict__ bs2,
    const float* __restrict__ W3, const float* __restrict__ bs3,
    float* out) {
    __shared__ float m[288];
    __shared__ float o1[128];
    __shared__ float o2[64];
    int g = blockIdx.x, t = threadIdx.x;
    int s = gstart[g], e = gend[g];
    int cint = e - s + 1;
    float cnt = (float)(cint < 1 ? 1 : cint);
    if (t < 128) {
        m[t] = pool_sum[g * 128 + t] / cnt;
        m[128 + t] = __int_as_float(pool_max[g * 128 + t]);
    }
    if (t < 32) m[256 + t] = gfeats[g * 32 + t];
    __syncthreads();
    float acc = bs1[t];
    for (int k = 0; k < 288; ++k) acc += m[k] * W1[k * 128 + t];
    o1[t] = fmaxf(acc, 0.f);
    __syncthreads();
    if (t < 64) {
        float a2 = bs2[t];
        for (int k = 0; k < 128; ++k) a2 += o1[k] * W2[k * 64 + t];
        o2[t] = fmaxf(a2, 0.f);
    }
    __syncthreads();
    if (t < 64) {
        float p = o2[t] * W3[t];
#pragma unroll
        for (int off = 32; off; off >>= 1) p += __shfl_down(p, off, 64);
        if (t == 0) out[g] = p + bs3[0];
    }
}

// ---------------- launch ----------------
extern "C" void kernel_launch(void* const* d_in, const int* in_sizes, int n_in,
                              void* d_out, int out_size, void* d_ws, size_t ws_size,
                              hipStream_t stream) {
    const float* x = (const float*)d_in[0];
    const int* ei = (const int*)d_in[1];
    const int* batch = (const int*)d_in[2];
    const float* gfeats = (const float*)d_in[3];
    const float *Wl[3], *Wr[3], *gma[3], *bta[3];
    for (int i = 0; i < 3; ++i) {
        Wl[i] = (const float*)d_in[4 + 5 * i];
        // d_in[5+5i] = bl (cancelled by BatchNorm; unused)
        Wr[i] = (const float*)d_in[6 + 5 * i];
        gma[i] = (const float*)d_in[7 + 5 * i];
        bta[i] = (const float*)d_in[8 + 5 * i];
    }
    const float* W1 = (const float*)d_in[19];
    const float* bs1 = (const float*)d_in[20];
    const float* W2 = (const float*)d_in[21];
    const float* bs2 = (const float*)d_in[22];
    const float* W3 = (const float*)d_in[23];
    const float* bs3 = (const float*)d_in[24];

    char* p = (char*)d_ws;
    auto alloc = [&](size_t bytes) -> char* {
        char* r = p;
        p += (bytes + 255) & ~(size_t)255;
        return r;
    };
    // total ~42.5 MB
    int* deg = (int*)alloc(NN * 4);
    int* row_start = (int*)alloc((NN + 1) * 4);
    int* cursor = (int*)alloc(NN * 4);
    int* col = (int*)alloc(NE * 4);
    int* gstart = (int*)alloc(NG * 4);
    int* gend = (int*)alloc(NG * 4);
    float* bnstats = (float*)alloc(3 * 256 * 4);
    float* pool_sum = (float*)alloc(NG * HID * 4);
    int* pool_max = (int*)alloc(NG * HID * 4);
    int* blocksum = (int*)alloc(SCAN_BLOCKS * 4);
    int* blockoff = (int*)alloc(SCAN_BLOCKS * 4);
    unsigned short* Bp = (unsigned short*)alloc(3 * 32768 * 2);
    unsigned short* xb = (unsigned short*)alloc((size_t)NN * 128 * 2);
    unsigned short* b0 = (unsigned short*)alloc((size_t)NN * 128 * 2);
    unsigned short* b1 = (unsigned short*)alloc((size_t)NN * 128 * 2);

    const int* srcv = ei;
    const int* dstv = ei + NE;

    k_setup<<<(NN * 64 + 255) / 256, 256, 0, stream>>>(x, xb, deg, gstart, gend,
                                                       bnstats, pool_sum, pool_max);
    k_histb<<<(NE + 255) / 256, 256, 0, stream>>>(dstv, deg, batch, gstart, gend);
    k_scan1<<<SCAN_BLOCKS, 256, 0, stream>>>(deg, blocksum);
    k_scan2<<<1, 256, 0, stream>>>(blocksum, blockoff, row_start);
    k_scan3<<<SCAN_BLOCKS, 256, 0, stream>>>(deg, blockoff, row_start, cursor);
    k_scatter<<<(NE + 255) / 256, 256, 0, stream>>>(srcv, dstv, cursor, col);
    k_prep<<<(3 * 32768 + 255) / 256, 256, 0, stream>>>(Wl[0], Wr[0], Wl[1], Wr[1], Wl[2], Wr[2], Bp);

    const unsigned short* hin = xb;
    unsigned short* work[3] = {b0, b1, b0};
    for (int l = 0; l < 3; ++l) {
        unsigned short* w = work[l];
        k_agg<<<(NN + 3) / 4, 256, 0, stream>>>(hin, row_start, col, w);
        k_gemm<<<GEMM_BLOCKS, 256, 0, stream>>>(w, (const unsigned short*)hin,
                                                Bp + l * 32768, bnstats + l * 256);
        k_norm<<<1024, 256, 0, stream>>>(w, bnstats + l * 256, gma[l], bta[l]);
        hin = w;
    }
    k_pool<<<NG * 8, 256, 0, stream>>>(hin, gstart, gend, pool_sum, pool_max);
    k_head<<<NG, 128, 0, stream>>>(pool_sum, pool_max, gstart, gend, gfeats,
                                   W1, bs1, W2, bs2, W3, bs3, (float*)d_out);
}

// Round 6
// 444.820 us; speedup vs baseline: 1.8034x; 1.1362x over previous
//
#include <hip/hip_runtime.h>
#include <stdint.h>

#define NN 50000
#define NE 800000
#define HID 128
#define NG 64
#define BN_EPS 1e-5f
#define SCAN_BLOCKS 196  // 196*256 = 50176 >= NN
#define GEMM_BLOCKS ((NN + 127) / 128)

typedef __bf16 bf16x8 __attribute__((ext_vector_type(8)));
typedef float floatx4 __attribute__((ext_vector_type(4)));

__device__ __forceinline__ float b2f(unsigned short u) {
    union { unsigned int i; float f; } x; x.i = ((unsigned int)u) << 16; return x.f;
}
__device__ __forceinline__ float blo(unsigned int d) { return __uint_as_float(d << 16); }
__device__ __forceinline__ float bhi(unsigned int d) { return __uint_as_float(d & 0xffff0000u); }
__device__ __forceinline__ unsigned short f2b(float f) {
    union { float f; unsigned int i; } x; x.f = f; unsigned int i = x.i;
    if ((i & 0x7f800000u) == 0x7f800000u) return (unsigned short)(i >> 16); // inf/nan
    return (unsigned short)((i + 0x7fffu + ((i >> 16) & 1u)) >> 16);        // RNE
}
__device__ __forceinline__ unsigned int pack2(float f0, float f1) {
    return (((unsigned int)f2b(f1)) << 16) | f2b(f0);
}

// ---------------- setup ----------------
__global__ void k_setup(const float* __restrict__ x, unsigned short* xb, int* deg,
                        int* gstart, int* gend, float* bnstats,
                        float* pool_sum, int* pool_max) {
    int i = blockIdx.x * 256 + threadIdx.x;
    if (i < NN * 64) {
        float2 v = ((const float2*)x)[i];
        ((unsigned int*)xb)[i] = pack2(v.x, v.y);
    }
    if (i < NN) deg[i] = 0;
    if (i < NG) { gstart[i] = NN; gend[i] = -1; }
    if (i < 3 * 256) bnstats[i] = 0.f;
    if (i < NG * HID) { pool_sum[i] = 0.f; pool_max[i] = 0; }
}

// fused: degree histogram (over NE) + per-graph row bounds (over NN)
__global__ void k_histb(const int* __restrict__ dst, int* deg,
                        const int* __restrict__ batch, int* gstart, int* gend) {
    int e = blockIdx.x * 256 + threadIdx.x;
    if (e < NE) atomicAdd(&deg[dst[e]], 1);
    if (e < NN) {
        int g = batch[e];
        if (e == 0 || batch[e - 1] != g) atomicMin(&gstart[g], e);
        if (e == NN - 1 || batch[e + 1] != g) atomicMax(&gend[g], e);
    }
}

// ---------------- hierarchical exclusive scan of deg ----------------
__global__ void k_scan1(const int* __restrict__ deg, int* blocksum) {
    __shared__ int lds[256];
    int t = threadIdx.x, i = blockIdx.x * 256 + t;
    lds[t] = (i < NN) ? deg[i] : 0;
    __syncthreads();
    for (int off = 128; off > 0; off >>= 1) {
        if (t < off) lds[t] += lds[t + off];
        __syncthreads();
    }
    if (t == 0) blocksum[blockIdx.x] = lds[0];
}

__global__ void k_scan2(const int* __restrict__ blocksum, int* blockoff, int* row_start) {
    __shared__ int lds[256];
    int t = threadIdx.x;
    int v = (t < SCAN_BLOCKS) ? blocksum[t] : 0;
    lds[t] = v;
    __syncthreads();
    for (int off = 1; off < 256; off <<= 1) {
        int u = (t >= off) ? lds[t - off] : 0;
        __syncthreads();
        lds[t] += u;
        __syncthreads();
    }
    if (t < SCAN_BLOCKS) blockoff[t] = lds[t] - v;  // exclusive
    if (t == 255) row_start[NN] = lds[255];         // total == NE
}

__global__ void k_scan3(const int* __restrict__ deg, const int* __restrict__ blockoff,
                        int* row_start, int* cursor) {
    __shared__ int lds[256];
    int t = threadIdx.x, i = blockIdx.x * 256 + t;
    int v = (i < NN) ? deg[i] : 0;
    lds[t] = v;
    __syncthreads();
    for (int off = 1; off < 256; off <<= 1) {
        int u = (t >= off) ? lds[t - off] : 0;
        __syncthreads();
        lds[t] += u;
        __syncthreads();
    }
    if (i < NN) {
        int ex = blockoff[blockIdx.x] + lds[t] - v;
        row_start[i] = ex;
        cursor[i] = ex;
    }
}

__global__ void k_scatter(const int* __restrict__ src, const int* __restrict__ dst,
                          int* cursor, int* col) {
    int e = blockIdx.x * 256 + threadIdx.x;
    if (e < NE) {
        int d = __builtin_nontemporal_load(&dst[e]);
        int s = __builtin_nontemporal_load(&src[e]);
        int p = atomicAdd(&cursor[d], 1);
        col[p] = s;  // regular store: let L2 merge line writebacks (NT store regressed, R5)
    }
}

// Pre-transpose fp32 [Wl;Wr] (256x128) into bf16 MFMA B-fragment order:
// Bp[layer][nt][kk][lane][j] = Wcat[kk*32+(lane>>4)*8+j][nt*16+(lane&15)]
__global__ void k_prep(const float* __restrict__ Wl0, const float* __restrict__ Wr0,
                       const float* __restrict__ Wl1, const float* __restrict__ Wr1,
                       const float* __restrict__ Wl2, const float* __restrict__ Wr2,
                       unsigned short* Bp) {
    int idx = blockIdx.x * 256 + threadIdx.x;
    if (idx >= 3 * 32768) return;
    int layer = idx >> 15;
    int r = idx & 32767;
    int nt = r >> 12, kk = (r >> 9) & 7, l = (r >> 3) & 63, j = r & 7;
    int k = kk * 32 + (l >> 4) * 8 + j;
    int n = nt * 16 + (l & 15);
    const float* Wl = layer == 0 ? Wl0 : (layer == 1 ? Wl1 : Wl2);
    const float* Wr = layer == 0 ? Wr0 : (layer == 1 ? Wr1 : Wr2);
    Bp[idx] = f2b((k < 128) ? Wl[k * 128 + n] : Wr[(k - 128) * 128 + n]);
}

// ---------------- per-layer kernels ----------------
// mean aggregation: 16 lanes per node (sub = 16B chunk of the 256B row), 4 nodes
// per wave. col[j] load is wave-coalesced broadcast (same addr across the group);
// no shuffles, no reduction — the group owns its node and writes the row directly.
// 3125 blocks x 4 waves -> ~49 waves/CU for gather latency hiding.
__global__ void k_agg(const unsigned short* __restrict__ h, const int* __restrict__ row_start,
                      const int* __restrict__ col, unsigned short* __restrict__ agg) {
    int wid = threadIdx.x >> 6, lane = threadIdx.x & 63;
    int slot = lane >> 4, sub = lane & 15;
    int node = (blockIdx.x * 4 + wid) * 4 + slot;  // 3125*4*4 == 50000 exactly
    int s = row_start[node], e = row_start[node + 1];
    const uint4* h4 = (const uint4*)h;  // one row = 16 uint4 (256B)
    float a0 = 0.f, a1 = 0.f, a2 = 0.f, a3 = 0.f, a4 = 0.f, a5 = 0.f, a6 = 0.f, a7 = 0.f;
    int j = s;
    for (; j + 2 <= e; j += 2) {
        int u0 = col[j], u1 = col[j + 1];
        uint4 v0 = h4[(size_t)u0 * 16 + sub];
        uint4 v1 = h4[(size_t)u1 * 16 + sub];
        a0 += blo(v0.x) + blo(v1.x);  a1 += bhi(v0.x) + bhi(v1.x);
        a2 += blo(v0.y) + blo(v1.y);  a3 += bhi(v0.y) + bhi(v1.y);
        a4 += blo(v0.z) + blo(v1.z);  a5 += bhi(v0.z) + bhi(v1.z);
        a6 += blo(v0.w) + blo(v1.w);  a7 += bhi(v0.w) + bhi(v1.w);
    }
    if (j < e) {
        int u = col[j];
        uint4 v = h4[(size_t)u * 16 + sub];
        a0 += blo(v.x);  a1 += bhi(v.x);
        a2 += blo(v.y);  a3 += bhi(v.y);
        a4 += blo(v.z);  a5 += bhi(v.z);
        a6 += blo(v.w);  a7 += bhi(v.w);
    }
    float inv = (e > s) ? 1.f / (float)(e - s) : 0.f;
    uint4 o;
    o.x = pack2(a0 * inv, a1 * inv);
    o.y = pack2(a2 * inv, a3 * inv);
    o.z = pack2(a4 * inv, a5 * inv);
    o.w = pack2(a6 * inv, a7 * inv);
    ((uint4*)agg)[(size_t)node * 16 + sub] = o;
}

// buf[M,128] <- [buf|h][M,256] @ Wcat[256,128], bf16 in-place; BN stats fused.
// Block = 4 waves, each wave 32 rows (2 M-tiles); B staged in LDS (64KB).
__global__ void __launch_bounds__(256) k_gemm(unsigned short* buf,
                                              const unsigned short* __restrict__ h,
                                              const unsigned short* __restrict__ Bp,
                                              float* bnstat) {
    __shared__ unsigned short Bs[32768];  // 64KB: B fragments; reused as float[256] stats
    int t = threadIdx.x;
    {
        const uint4* s4 = (const uint4*)Bp;
        uint4* d4 = (uint4*)Bs;
        for (int i = t; i < 4096; i += 256) d4[i] = s4[i];
    }
    __syncthreads();
    int wid = t >> 6, lane = t & 63;
    int m = lane & 15, q = lane >> 4;
    int mbase = blockIdx.x * 128 + wid * 32;
    bool active = mbase < NN;
    float s[8] = {0, 0, 0, 0, 0, 0, 0, 0};
    float ss[8] = {0, 0, 0, 0, 0, 0, 0, 0};
    if (active) {
        int row0 = mbase + m;                       // always < NN when active
        int row1 = min(mbase + 16 + m, NN - 1);     // clamp tail (garbage rows masked later)
        const bf16x8* Abuf = (const bf16x8*)buf;
        const bf16x8* Ah = (const bf16x8*)h;
        const bf16x8* B = (const bf16x8*)Bs;
        size_t b0 = (size_t)row0 * 16, b1 = (size_t)row1 * 16;
        floatx4 acc[2][8];
#pragma unroll
        for (int mt = 0; mt < 2; ++mt)
#pragma unroll
            for (int nt = 0; nt < 8; ++nt) acc[mt][nt] = (floatx4){0.f, 0.f, 0.f, 0.f};
#pragma unroll
        for (int kk = 0; kk < 8; ++kk) {
            bf16x8 a0 = (kk < 4) ? Abuf[b0 + kk * 4 + q] : Ah[b0 + (kk - 4) * 4 + q];
            bf16x8 a1 = (kk < 4) ? Abuf[b1 + kk * 4 + q] : Ah[b1 + (kk - 4) * 4 + q];
#pragma unroll
            for (int nt = 0; nt < 8; ++nt) {
                bf16x8 b = B[(nt * 8 + kk) * 64 + lane];
                acc[0][nt] = __builtin_amdgcn_mfma_f32_16x16x32_bf16(a0, b, acc[0][nt], 0, 0, 0);
                acc[1][nt] = __builtin_amdgcn_mfma_f32_16x16x32_bf16(a1, b, acc[1][nt], 0, 0, 0);
            }
        }
        // epilogue: store bf16 + accumulate per-column stats
#pragma unroll
        for (int mt = 0; mt < 2; ++mt)
#pragma unroll
            for (int nt = 0; nt < 8; ++nt) {
                int c = nt * 16 + m;  // C/D: col = lane&15
#pragma unroll
                for (int reg = 0; reg < 4; ++reg) {
                    int r = mbase + mt * 16 + q * 4 + reg;  // C/D: row = quad*4+reg
                    if (r < NN) {
                        float v = acc[mt][nt][reg];
                        buf[(size_t)r * 128 + c] = f2b(v);
                        s[nt] += v;
                        ss[nt] += v * v;
                    }
                }
            }
#pragma unroll
        for (int nt = 0; nt < 8; ++nt) {
            s[nt] += __shfl_xor(s[nt], 16, 64);  s[nt] += __shfl_xor(s[nt], 32, 64);
            ss[nt] += __shfl_xor(ss[nt], 16, 64); ss[nt] += __shfl_xor(ss[nt], 32, 64);
        }
    }
    __syncthreads();  // all waves done reading Bs
    float* stf = (float*)Bs;
    if (t < 256) stf[t] = 0.f;
    __syncthreads();
    if (active && lane < 16) {
#pragma unroll
        for (int nt = 0; nt < 8; ++nt) {
            int c = nt * 16 + m;
            atomicAdd(&stf[c], s[nt]);
            atomicAdd(&stf[128 + c], ss[nt]);
        }
    }
    __syncthreads();
    if (t < 256) atomicAdd(&bnstat[t], stf[t]);
}

// BN+ReLU in place (bf16 buffer), gamma/beta fp32
__global__ void k_norm(unsigned short* buf, const float* __restrict__ bnstat,
                       const float* __restrict__ gamma, const float* __restrict__ beta) {
    __shared__ float s_sc[128], s_sh[128];
    int t = threadIdx.x;
    if (t < 128) {
        float mu = bnstat[t] * (1.f / NN);
        float var = bnstat[128 + t] * (1.f / NN) - mu * mu;
        float sc = gamma[t] * rsqrtf(var + BN_EPS);
        s_sc[t] = sc;
        s_sh[t] = beta[t] - mu * sc;
    }
    __syncthreads();
    unsigned int* p2 = (unsigned int*)buf;
    int total = NN * 64;
    for (int idx = blockIdx.x * blockDim.x + t; idx < total; idx += gridDim.x * blockDim.x) {
        int c2 = (idx & 63) * 2;
        unsigned int v = p2[idx];
        float r0 = fmaxf(b2f((unsigned short)(v & 0xffffu)) * s_sc[c2] + s_sh[c2], 0.f);
        float r1 = fmaxf(b2f((unsigned short)(v >> 16)) * s_sc[c2 + 1] + s_sh[c2 + 1], 0.f);
        p2[idx] = pack2(r0, r1);
    }
}

// ---------------- pooling + head ----------------
__global__ void k_pool(const unsigned short* __restrict__ h, const int* __restrict__ gstart,
                       const int* __restrict__ gend, float* pool_sum, int* pool_max) {
    int g = blockIdx.x >> 3, chunk = blockIdx.x & 7;
    int s = gstart[g], e = gend[g];
    if (s > e) return;
    int cnt = e - s + 1;
    int per = (cnt + 7) >> 3;
    int r0 = s + chunk * per;
    int r1 = min(r0 + per, e + 1);
    int c = threadIdx.x & 127, half = threadIdx.x >> 7;
    float sm = 0.f, mx = 0.f;  // post-relu values are >= 0
    for (int r = r0 + half; r < r1; r += 2) {
        float v = b2f(h[(size_t)r * 128 + c]);
        sm += v;
        mx = fmaxf(mx, v);
    }
    atomicAdd(&pool_sum[g * 128 + c], sm);
    atomicMax(&pool_max[g * 128 + c], __float_as_int(mx));  // valid for >=0 floats
}

__global__ void __launch_bounds__(128) k_head(
    const float* __restrict__ pool_sum, const int* __restrict__ pool_max,
    const int* __restrict__ gstart, const int* __restrict__ gend,
    const float* __restrict__ gfeats,
    const float* __restrict__ W1, const float* __restrict__ bs1,
    const float* __restrict__ W2, const float* __restrict__ bs2,
    const float* __restrict__ W3, const float* __restrict__ bs3,
    float* out) {
    __shared__ float m[288];
    __shared__ float o1[128];
    __shared__ float o2[64];
    int g = blockIdx.x, t = threadIdx.x;
    int s = gstart[g], e = gend[g];
    int cint = e - s + 1;
    float cnt = (float)(cint < 1 ? 1 : cint);
    if (t < 128) {
        m[t] = pool_sum[g * 128 + t] / cnt;
        m[128 + t] = __int_as_float(pool_max[g * 128 + t]);
    }
    if (t < 32) m[256 + t] = gfeats[g * 32 + t];
    __syncthreads();
    float acc = bs1[t];
    for (int k = 0; k < 288; ++k) acc += m[k] * W1[k * 128 + t];
    o1[t] = fmaxf(acc, 0.f);
    __syncthreads();
    if (t < 64) {
        float a2 = bs2[t];
        for (int k = 0; k < 128; ++k) a2 += o1[k] * W2[k * 64 + t];
        o2[t] = fmaxf(a2, 0.f);
    }
    __syncthreads();
    if (t < 64) {
        float p = o2[t] * W3[t];
#pragma unroll
        for (int off = 32; off; off >>= 1) p += __shfl_down(p, off, 64);
        if (t == 0) out[g] = p + bs3[0];
    }
}

// ---------------- launch ----------------
extern "C" void kernel_launch(void* const* d_in, const int* in_sizes, int n_in,
                              void* d_out, int out_size, void* d_ws, size_t ws_size,
                              hipStream_t stream) {
    const float* x = (const float*)d_in[0];
    const int* ei = (const int*)d_in[1];
    const int* batch = (const int*)d_in[2];
    const float* gfeats = (const float*)d_in[3];
    const float *Wl[3], *Wr[3], *gma[3], *bta[3];
    for (int i = 0; i < 3; ++i) {
        Wl[i] = (const float*)d_in[4 + 5 * i];
        // d_in[5+5i] = bl (cancelled by BatchNorm; unused)
        Wr[i] = (const float*)d_in[6 + 5 * i];
        gma[i] = (const float*)d_in[7 + 5 * i];
        bta[i] = (const float*)d_in[8 + 5 * i];
    }
    const float* W1 = (const float*)d_in[19];
    const float* bs1 = (const float*)d_in[20];
    const float* W2 = (const float*)d_in[21];
    const float* bs2 = (const float*)d_in[22];
    const float* W3 = (const float*)d_in[23];
    const float* bs3 = (const float*)d_in[24];

    char* p = (char*)d_ws;
    auto alloc = [&](size_t bytes) -> char* {
        char* r = p;
        p += (bytes + 255) & ~(size_t)255;
        return r;
    };
    // total ~42.5 MB
    int* deg = (int*)alloc(NN * 4);
    int* row_start = (int*)alloc((NN + 1) * 4);
    int* cursor = (int*)alloc(NN * 4);
    int* col = (int*)alloc(NE * 4);
    int* gstart = (int*)alloc(NG * 4);
    int* gend = (int*)alloc(NG * 4);
    float* bnstats = (float*)alloc(3 * 256 * 4);
    float* pool_sum = (float*)alloc(NG * HID * 4);
    int* pool_max = (int*)alloc(NG * HID * 4);
    int* blocksum = (int*)alloc(SCAN_BLOCKS * 4);
    int* blockoff = (int*)alloc(SCAN_BLOCKS * 4);
    unsigned short* Bp = (unsigned short*)alloc(3 * 32768 * 2);
    unsigned short* xb = (unsigned short*)alloc((size_t)NN * 128 * 2);
    unsigned short* b0 = (unsigned short*)alloc((size_t)NN * 128 * 2);
    unsigned short* b1 = (unsigned short*)alloc((size_t)NN * 128 * 2);

    const int* srcv = ei;
    const int* dstv = ei + NE;

    k_setup<<<(NN * 64 + 255) / 256, 256, 0, stream>>>(x, xb, deg, gstart, gend,
                                                       bnstats, pool_sum, pool_max);
    k_histb<<<(NE + 255) / 256, 256, 0, stream>>>(dstv, deg, batch, gstart, gend);
    k_scan1<<<SCAN_BLOCKS, 256, 0, stream>>>(deg, blocksum);
    k_scan2<<<1, 256, 0, stream>>>(blocksum, blockoff, row_start);
    k_scan3<<<SCAN_BLOCKS, 256, 0, stream>>>(deg, blockoff, row_start, cursor);
    k_scatter<<<(NE + 255) / 256, 256, 0, stream>>>(srcv, dstv, cursor, col);
    k_prep<<<(3 * 32768 + 255) / 256, 256, 0, stream>>>(Wl[0], Wr[0], Wl[1], Wr[1], Wl[2], Wr[2], Bp);

    const unsigned short* hin = xb;
    unsigned short* work[3] = {b0, b1, b0};
    for (int l = 0; l < 3; ++l) {
        unsigned short* w = work[l];
        k_agg<<<(NN + 15) / 16, 256, 0, stream>>>(hin, row_start, col, w);
        k_gemm<<<GEMM_BLOCKS, 256, 0, stream>>>(w, (const unsigned short*)hin,
                                                Bp + l * 32768, bnstats + l * 256);
        k_norm<<<1024, 256, 0, stream>>>(w, bnstats + l * 256, gma[l], bta[l]);
        hin = w;
    }
    k_pool<<<NG * 8, 256, 0, stream>>>(hin, gstart, gend, pool_sum, pool_max);
    k_head<<<NG, 128, 0, stream>>>(pool_sum, pool_max, gstart, gend, gfeats,
                                   W1, bs1, W2, bs2, W3, bs3, (float*)d_out);
}

// Round 7
// 423.360 us; speedup vs baseline: 1.8948x; 1.0507x over previous
//
#include <hip/hip_runtime.h>
#include <stdint.h>

#define NN 50000
#define NE 800000
#define HID 128
#define NG 64
#define BN_EPS 1e-5f
#define SCAN_BLOCKS 196  // 196*256 = 50176 >= NN
#define GEMM_BLOCKS ((NN + 127) / 128)
#define SC_NB 8                                  // scatter buckets (== XCD count)
#define SC_BSZ ((NN + SC_NB - 1) / SC_NB)        // 6250 nodes per bucket
#define SC_CHUNK 4096                            // edges per block
#define SC_CHUNKS ((NE + SC_CHUNK - 1) / SC_CHUNK)

typedef __bf16 bf16x8 __attribute__((ext_vector_type(8)));
typedef float floatx4 __attribute__((ext_vector_type(4)));

__device__ __forceinline__ float b2f(unsigned short u) {
    union { unsigned int i; float f; } x; x.i = ((unsigned int)u) << 16; return x.f;
}
__device__ __forceinline__ float blo(unsigned int d) { return __uint_as_float(d << 16); }
__device__ __forceinline__ float bhi(unsigned int d) { return __uint_as_float(d & 0xffff0000u); }
__device__ __forceinline__ unsigned short f2b(float f) {
    union { float f; unsigned int i; } x; x.f = f; unsigned int i = x.i;
    if ((i & 0x7f800000u) == 0x7f800000u) return (unsigned short)(i >> 16); // inf/nan
    return (unsigned short)((i + 0x7fffu + ((i >> 16) & 1u)) >> 16);        // RNE
}
__device__ __forceinline__ unsigned int pack2(float f0, float f1) {
    return (((unsigned int)f2b(f1)) << 16) | f2b(f0);
}

// ---------------- setup ----------------
__global__ void k_setup(const float* __restrict__ x, unsigned short* xb, int* deg,
                        int* gstart, int* gend, float* bnstats,
                        float* pool_sum, int* pool_max) {
    int i = blockIdx.x * 256 + threadIdx.x;
    if (i < NN * 64) {
        float2 v = ((const float2*)x)[i];
        ((unsigned int*)xb)[i] = pack2(v.x, v.y);
    }
    if (i < NN) deg[i] = 0;
    if (i < NG) { gstart[i] = NN; gend[i] = -1; }
    if (i < 3 * 256) bnstats[i] = 0.f;
    if (i < NG * HID) { pool_sum[i] = 0.f; pool_max[i] = 0; }
}

// fused: degree histogram (over NE) + per-graph row bounds (over NN)
__global__ void k_histb(const int* __restrict__ dst, int* deg,
                        const int* __restrict__ batch, int* gstart, int* gend) {
    int e = blockIdx.x * 256 + threadIdx.x;
    if (e < NE) atomicAdd(&deg[dst[e]], 1);
    if (e < NN) {
        int g = batch[e];
        if (e == 0 || batch[e - 1] != g) atomicMin(&gstart[g], e);
        if (e == NN - 1 || batch[e + 1] != g) atomicMax(&gend[g], e);
    }
}

// ---------------- hierarchical exclusive scan of deg ----------------
__global__ void k_scan1(const int* __restrict__ deg, int* blocksum) {
    __shared__ int lds[256];
    int t = threadIdx.x, i = blockIdx.x * 256 + t;
    lds[t] = (i < NN) ? deg[i] : 0;
    __syncthreads();
    for (int off = 128; off > 0; off >>= 1) {
        if (t < off) lds[t] += lds[t + off];
        __syncthreads();
    }
    if (t == 0) blocksum[blockIdx.x] = lds[0];
}

__global__ void k_scan2(const int* __restrict__ blocksum, int* blockoff, int* row_start) {
    __shared__ int lds[256];
    int t = threadIdx.x;
    int v = (t < SCAN_BLOCKS) ? blocksum[t] : 0;
    lds[t] = v;
    __syncthreads();
    for (int off = 1; off < 256; off <<= 1) {
        int u = (t >= off) ? lds[t - off] : 0;
        __syncthreads();
        lds[t] += u;
        __syncthreads();
    }
    if (t < SCAN_BLOCKS) blockoff[t] = lds[t] - v;  // exclusive
    if (t == 255) row_start[NN] = lds[255];         // total == NE
}

__global__ void k_scan3(const int* __restrict__ deg, const int* __restrict__ blockoff,
                        int* row_start, int* cursor) {
    __shared__ int lds[256];
    int t = threadIdx.x, i = blockIdx.x * 256 + t;
    int v = (i < NN) ? deg[i] : 0;
    lds[t] = v;
    __syncthreads();
    for (int off = 1; off < 256; off <<= 1) {
        int u = (t >= off) ? lds[t - off] : 0;
        __syncthreads();
        lds[t] += u;
        __syncthreads();
    }
    if (i < NN) {
        int ex = blockoff[blockIdx.x] + lds[t] - v;
        row_start[i] = ex;
        cursor[i] = ex;
    }
}

// XCD-bucketized scatter: block = (chunk, bucket); bucket = blockIdx.x & 7 so
// consecutive blocks (round-robin across XCDs) own disjoint dst ranges ->
// col-writes for one 400KB slice concentrate in one XCD's L2 and merge before
// writeback. Each edge chunk is re-read once per bucket (L3-served, sequential).
__global__ void k_scatter(const int* __restrict__ src, const int* __restrict__ dst,
                          int* cursor, int* col) {
    int bucket = blockIdx.x & (SC_NB - 1);
    int chunk = blockIdx.x / SC_NB;
    int lo = bucket * SC_BSZ, hi = lo + SC_BSZ;
    int base = chunk * SC_CHUNK;
#pragma unroll
    for (int i = 0; i < SC_CHUNK / 256; ++i) {
        int e = base + i * 256 + threadIdx.x;
        if (e < NE) {
            int d = dst[e];
            if (d >= lo && d < hi) {
                int p = atomicAdd(&cursor[d], 1);
                col[p] = src[e];
            }
        }
    }
}

// Pre-transpose fp32 [Wl;Wr] (256x128) into bf16 MFMA B-fragment order:
// Bp[layer][nt][kk][lane][j] = Wcat[kk*32+(lane>>4)*8+j][nt*16+(lane&15)]
__global__ void k_prep(const float* __restrict__ Wl0, const float* __restrict__ Wr0,
                       const float* __restrict__ Wl1, const float* __restrict__ Wr1,
                       const float* __restrict__ Wl2, const float* __restrict__ Wr2,
                       unsigned short* Bp) {
    int idx = blockIdx.x * 256 + threadIdx.x;
    if (idx >= 3 * 32768) return;
    int layer = idx >> 15;
    int r = idx & 32767;
    int nt = r >> 12, kk = (r >> 9) & 7, l = (r >> 3) & 63, j = r & 7;
    int k = kk * 32 + (l >> 4) * 8 + j;
    int n = nt * 16 + (l & 15);
    const float* Wl = layer == 0 ? Wl0 : (layer == 1 ? Wl1 : Wl2);
    const float* Wr = layer == 0 ? Wr0 : (layer == 1 ? Wr1 : Wr2);
    Bp[idx] = f2b((k < 128) ? Wl[k * 128 + n] : Wr[(k - 128) * 128 + n]);
}

// ---------------- per-layer kernels ----------------
// mean aggregation: 16 lanes per node (sub = 16B chunk of the 256B row), 4 nodes
// per wave; col[j] load is group-coalesced broadcast; no shuffles/reduction.
__global__ void k_agg(const unsigned short* __restrict__ h, const int* __restrict__ row_start,
                      const int* __restrict__ col, unsigned short* __restrict__ agg) {
    int wid = threadIdx.x >> 6, lane = threadIdx.x & 63;
    int slot = lane >> 4, sub = lane & 15;
    int node = (blockIdx.x * 4 + wid) * 4 + slot;  // 3125*4*4 == 50000 exactly
    int s = row_start[node], e = row_start[node + 1];
    const uint4* h4 = (const uint4*)h;  // one row = 16 uint4 (256B)
    float a0 = 0.f, a1 = 0.f, a2 = 0.f, a3 = 0.f, a4 = 0.f, a5 = 0.f, a6 = 0.f, a7 = 0.f;
    int j = s;
    for (; j + 2 <= e; j += 2) {
        int u0 = col[j], u1 = col[j + 1];
        uint4 v0 = h4[(size_t)u0 * 16 + sub];
        uint4 v1 = h4[(size_t)u1 * 16 + sub];
        a0 += blo(v0.x) + blo(v1.x);  a1 += bhi(v0.x) + bhi(v1.x);
        a2 += blo(v0.y) + blo(v1.y);  a3 += bhi(v0.y) + bhi(v1.y);
        a4 += blo(v0.z) + blo(v1.z);  a5 += bhi(v0.z) + bhi(v1.z);
        a6 += blo(v0.w) + blo(v1.w);  a7 += bhi(v0.w) + bhi(v1.w);
    }
    if (j < e) {
        int u = col[j];
        uint4 v = h4[(size_t)u * 16 + sub];
        a0 += blo(v.x);  a1 += bhi(v.x);
        a2 += blo(v.y);  a3 += bhi(v.y);
        a4 += blo(v.z);  a5 += bhi(v.z);
        a6 += blo(v.w);  a7 += bhi(v.w);
    }
    float inv = (e > s) ? 1.f / (float)(e - s) : 0.f;
    uint4 o;
    o.x = pack2(a0 * inv, a1 * inv);
    o.y = pack2(a2 * inv, a3 * inv);
    o.z = pack2(a4 * inv, a5 * inv);
    o.w = pack2(a6 * inv, a7 * inv);
    ((uint4*)agg)[(size_t)node * 16 + sub] = o;
}

// buf[M,128] <- [buf|h][M,256] @ Wcat[256,128], bf16 in-place; BN stats fused.
// Block = 4 waves, each wave 32 rows (2 M-tiles); B staged in LDS (64KB).
__global__ void __launch_bounds__(256) k_gemm(unsigned short* buf,
                                              const unsigned short* __restrict__ h,
                                              const unsigned short* __restrict__ Bp,
                                              float* bnstat) {
    __shared__ unsigned short Bs[32768];  // 64KB: B fragments; reused as float[256] stats
    int t = threadIdx.x;
    {
        const uint4* s4 = (const uint4*)Bp;
        uint4* d4 = (uint4*)Bs;
        for (int i = t; i < 4096; i += 256) d4[i] = s4[i];
    }
    __syncthreads();
    int wid = t >> 6, lane = t & 63;
    int m = lane & 15, q = lane >> 4;
    int mbase = blockIdx.x * 128 + wid * 32;
    bool active = mbase < NN;
    float s[8] = {0, 0, 0, 0, 0, 0, 0, 0};
    float ss[8] = {0, 0, 0, 0, 0, 0, 0, 0};
    if (active) {
        int row0 = mbase + m;                       // always < NN when active
        int row1 = min(mbase + 16 + m, NN - 1);     // clamp tail (garbage rows masked later)
        const bf16x8* Abuf = (const bf16x8*)buf;
        const bf16x8* Ah = (const bf16x8*)h;
        const bf16x8* B = (const bf16x8*)Bs;
        size_t b0 = (size_t)row0 * 16, b1 = (size_t)row1 * 16;
        floatx4 acc[2][8];
#pragma unroll
        for (int mt = 0; mt < 2; ++mt)
#pragma unroll
            for (int nt = 0; nt < 8; ++nt) acc[mt][nt] = (floatx4){0.f, 0.f, 0.f, 0.f};
#pragma unroll
        for (int kk = 0; kk < 8; ++kk) {
            bf16x8 a0 = (kk < 4) ? Abuf[b0 + kk * 4 + q] : Ah[b0 + (kk - 4) * 4 + q];
            bf16x8 a1 = (kk < 4) ? Abuf[b1 + kk * 4 + q] : Ah[b1 + (kk - 4) * 4 + q];
#pragma unroll
            for (int nt = 0; nt < 8; ++nt) {
                bf16x8 b = B[(nt * 8 + kk) * 64 + lane];
                acc[0][nt] = __builtin_amdgcn_mfma_f32_16x16x32_bf16(a0, b, acc[0][nt], 0, 0, 0);
                acc[1][nt] = __builtin_amdgcn_mfma_f32_16x16x32_bf16(a1, b, acc[1][nt], 0, 0, 0);
            }
        }
        // epilogue: store bf16 + accumulate per-column stats
#pragma unroll
        for (int mt = 0; mt < 2; ++mt)
#pragma unroll
            for (int nt = 0; nt < 8; ++nt) {
                int c = nt * 16 + m;  // C/D: col = lane&15
#pragma unroll
                for (int reg = 0; reg < 4; ++reg) {
                    int r = mbase + mt * 16 + q * 4 + reg;  // C/D: row = quad*4+reg
                    if (r < NN) {
                        float v = acc[mt][nt][reg];
                        buf[(size_t)r * 128 + c] = f2b(v);
                        s[nt] += v;
                        ss[nt] += v * v;
                    }
                }
            }
#pragma unroll
        for (int nt = 0; nt < 8; ++nt) {
            s[nt] += __shfl_xor(s[nt], 16, 64);  s[nt] += __shfl_xor(s[nt], 32, 64);
            ss[nt] += __shfl_xor(ss[nt], 16, 64); ss[nt] += __shfl_xor(ss[nt], 32, 64);
        }
    }
    __syncthreads();  // all waves done reading Bs
    float* stf = (float*)Bs;
    if (t < 256) stf[t] = 0.f;
    __syncthreads();
    if (active && lane < 16) {
#pragma unroll
        for (int nt = 0; nt < 8; ++nt) {
            int c = nt * 16 + m;
            atomicAdd(&stf[c], s[nt]);
            atomicAdd(&stf[128 + c], ss[nt]);
        }
    }
    __syncthreads();
    if (t < 256) atomicAdd(&bnstat[t], stf[t]);
}

// BN+ReLU in place (bf16 buffer), gamma/beta fp32
__global__ void k_norm(unsigned short* buf, const float* __restrict__ bnstat,
                       const float* __restrict__ gamma, const float* __restrict__ beta) {
    __shared__ float s_sc[128], s_sh[128];
    int t = threadIdx.x;
    if (t < 128) {
        float mu = bnstat[t] * (1.f / NN);
        float var = bnstat[128 + t] * (1.f / NN) - mu * mu;
        float sc = gamma[t] * rsqrtf(var + BN_EPS);
        s_sc[t] = sc;
        s_sh[t] = beta[t] - mu * sc;
    }
    __syncthreads();
    unsigned int* p2 = (unsigned int*)buf;
    int total = NN * 64;
    for (int idx = blockIdx.x * blockDim.x + t; idx < total; idx += gridDim.x * blockDim.x) {
        int c2 = (idx & 63) * 2;
        unsigned int v = p2[idx];
        float r0 = fmaxf(b2f((unsigned short)(v & 0xffffu)) * s_sc[c2] + s_sh[c2], 0.f);
        float r1 = fmaxf(b2f((unsigned short)(v >> 16)) * s_sc[c2 + 1] + s_sh[c2 + 1], 0.f);
        p2[idx] = pack2(r0, r1);
    }
}

// ---------------- pooling + head ----------------
__global__ void k_pool(const unsigned short* __restrict__ h, const int* __restrict__ gstart,
                       const int* __restrict__ gend, float* pool_sum, int* pool_max) {
    int g = blockIdx.x >> 3, chunk = blockIdx.x & 7;
    int s = gstart[g], e = gend[g];
    if (s > e) return;
    int cnt = e - s + 1;
    int per = (cnt + 7) >> 3;
    int r0 = s + chunk * per;
    int r1 = min(r0 + per, e + 1);
    int c = threadIdx.x & 127, half = threadIdx.x >> 7;
    float sm = 0.f, mx = 0.f;  // post-relu values are >= 0
    for (int r = r0 + half; r < r1; r += 2) {
        float v = b2f(h[(size_t)r * 128 + c]);
        sm += v;
        mx = fmaxf(mx, v);
    }
    atomicAdd(&pool_sum[g * 128 + c], sm);
    atomicMax(&pool_max[g * 128 + c], __float_as_int(mx));  // valid for >=0 floats
}

__global__ void __launch_bounds__(128) k_head(
    const float* __restrict__ pool_sum, const int* __restrict__ pool_max,
    const int* __restrict__ gstart, const int* __restrict__ gend,
    const float* __restrict__ gfeats,
    const float* __restrict__ W1, const float* __restrict__ bs1,
    const float* __restrict__ W2, const float* __restrict__ bs2,
    const float* __restrict__ W3, const float* __restrict__ bs3,
    float* out) {
    __shared__ float m[288];
    __shared__ float o1[128];
    __shared__ float o2[64];
    int g = blockIdx.x, t = threadIdx.x;
    int s = gstart[g], e = gend[g];
    int cint = e - s + 1;
    float cnt = (float)(cint < 1 ? 1 : cint);
    if (t < 128) {
        m[t] = pool_sum[g * 128 + t] / cnt;
        m[128 + t] = __int_as_float(pool_max[g * 128 + t]);
    }
    if (t < 32) m[256 + t] = gfeats[g * 32 + t];
    __syncthreads();
    float acc = bs1[t];
    for (int k = 0; k < 288; ++k) acc += m[k] * W1[k * 128 + t];
    o1[t] = fmaxf(acc, 0.f);
    __syncthreads();
    if (t < 64) {
        float a2 = bs2[t];
        for (int k = 0; k < 128; ++k) a2 += o1[k] * W2[k * 64 + t];
        o2[t] = fmaxf(a2, 0.f);
    }
    __syncthreads();
    if (t < 64) {
        float p = o2[t] * W3[t];
#pragma unroll
        for (int off = 32; off; off >>= 1) p += __shfl_down(p, off, 64);
        if (t == 0) out[g] = p + bs3[0];
    }
}

// ---------------- launch ----------------
extern "C" void kernel_launch(void* const* d_in, const int* in_sizes, int n_in,
                              void* d_out, int out_size, void* d_ws, size_t ws_size,
                              hipStream_t stream) {
    const float* x = (const float*)d_in[0];
    const int* ei = (const int*)d_in[1];
    const int* batch = (const int*)d_in[2];
    const float* gfeats = (const float*)d_in[3];
    const float *Wl[3], *Wr[3], *gma[3], *bta[3];
    for (int i = 0; i < 3; ++i) {
        Wl[i] = (const float*)d_in[4 + 5 * i];
        // d_in[5+5i] = bl (cancelled by BatchNorm; unused)
        Wr[i] = (const float*)d_in[6 + 5 * i];
        gma[i] = (const float*)d_in[7 + 5 * i];
        bta[i] = (const float*)d_in[8 + 5 * i];
    }
    const float* W1 = (const float*)d_in[19];
    const float* bs1 = (const float*)d_in[20];
    const float* W2 = (const float*)d_in[21];
    const float* bs2 = (const float*)d_in[22];
    const float* W3 = (const float*)d_in[23];
    const float* bs3 = (const float*)d_in[24];

    char* p = (char*)d_ws;
    auto alloc = [&](size_t bytes) -> char* {
        char* r = p;
        p += (bytes + 255) & ~(size_t)255;
        return r;
    };
    // total ~42.5 MB
    int* deg = (int*)alloc(NN * 4);
    int* row_start = (int*)alloc((NN + 1) * 4);
    int* cursor = (int*)alloc(NN * 4);
    int* col = (int*)alloc(NE * 4);
    int* gstart = (int*)alloc(NG * 4);
    int* gend = (int*)alloc(NG * 4);
    float* bnstats = (float*)alloc(3 * 256 * 4);
    float* pool_sum = (float*)alloc(NG * HID * 4);
    int* pool_max = (int*)alloc(NG * HID * 4);
    int* blocksum = (int*)alloc(SCAN_BLOCKS * 4);
    int* blockoff = (int*)alloc(SCAN_BLOCKS * 4);
    unsigned short* Bp = (unsigned short*)alloc(3 * 32768 * 2);
    unsigned short* xb = (unsigned short*)alloc((size_t)NN * 128 * 2);
    unsigned short* b0 = (unsigned short*)alloc((size_t)NN * 128 * 2);
    unsigned short* b1 = (unsigned short*)alloc((size_t)NN * 128 * 2);

    const int* srcv = ei;
    const int* dstv = ei + NE;

    k_setup<<<(NN * 64 + 255) / 256, 256, 0, stream>>>(x, xb, deg, gstart, gend,
                                                       bnstats, pool_sum, pool_max);
    k_histb<<<(NE + 255) / 256, 256, 0, stream>>>(dstv, deg, batch, gstart, gend);
    k_scan1<<<SCAN_BLOCKS, 256, 0, stream>>>(deg, blocksum);
    k_scan2<<<1, 256, 0, stream>>>(blocksum, blockoff, row_start);
    k_scan3<<<SCAN_BLOCKS, 256, 0, stream>>>(deg, blockoff, row_start, cursor);
    k_scatter<<<SC_CHUNKS * SC_NB, 256, 0, stream>>>(srcv, dstv, cursor, col);
    k_prep<<<(3 * 32768 + 255) / 256, 256, 0, stream>>>(Wl[0], Wr[0], Wl[1], Wr[1], Wl[2], Wr[2], Bp);

    const unsigned short* hin = xb;
    unsigned short* work[3] = {b0, b1, b0};
    for (int l = 0; l < 3; ++l) {
        unsigned short* w = work[l];
        k_agg<<<(NN + 15) / 16, 256, 0, stream>>>(hin, row_start, col, w);
        k_gemm<<<GEMM_BLOCKS, 256, 0, stream>>>(w, (const unsigned short*)hin,
                                                Bp + l * 32768, bnstats + l * 256);
        k_norm<<<1024, 256, 0, stream>>>(w, bnstats + l * 256, gma[l], bta[l]);
        hin = w;
    }
    k_pool<<<NG * 8, 256, 0, stream>>>(hin, gstart, gend, pool_sum, pool_max);
    k_head<<<NG, 128, 0, stream>>>(pool_sum, pool_max, gstart, gend, gfeats,
                                   W1, bs1, W2, bs2, W3, bs3, (float*)d_out);
}